// Round 12
// baseline (417.780 us; speedup 1.0000x reference)
//
#include <hip/hip_runtime.h>
#include <hip/hip_bf16.h>
#include <stdint.h>

// Problem dims (fixed)
#define NB 8
#define NS 2048
#define ND 1024
#define NH 4096
#define NE 8
#define NTOK (NB*NS)   // 16384 tokens

typedef __bf16 bf16;
typedef bf16 bf16x8 __attribute__((ext_vector_type(8)));
typedef float f32x4 __attribute__((ext_vector_type(4)));

// ws layout: meta[512] ints + perm[16384] at meta+512, then:
static const size_t OFF_XB  = 128 * 1024;                          // bf16 xb [NTOK][ND]  (token order)
static const size_t OFF_WTE = OFF_XB  + (size_t)NTOK * ND * 2;     // bf16 wte[NE][NH][ND]
static const size_t OFF_WTO = OFF_WTE + (size_t)NE * NH * ND * 2;  // bf16 wto[ND][NH]
static const size_t OFF_HB  = OFF_WTO + (size_t)ND * NH * 2;       // bf16 hb [NTOK][NH] (permuted rows)
static const size_t WS_NEED = OFF_HB  + (size_t)NTOK * NH * 2;

#define GLDS16(src, dst) __builtin_amdgcn_global_load_lds( \
    (__attribute__((address_space(1))) void*)(void*)(src), \
    (__attribute__((address_space(3))) void*)(dst), 16, 0, 0)

// =====================================================================
// ONE prep kernel: block 0 = routing; blocks [1,8192] = x f32->bf16 cvt;
// blocks [8193,45056] = weight transposes.  (R11-validated, at HBM BW)
// =====================================================================
__global__ void k_prep(const int* __restrict__ assign, const float* __restrict__ x,
                       const float* __restrict__ W_e, const float* __restrict__ W_out,
                       int* __restrict__ meta, bf16* __restrict__ xb,
                       bf16* __restrict__ wte, bf16* __restrict__ wto) {
    int b = blockIdx.x;
    int tid = threadIdx.x;
    if (b == 0) {
        __shared__ int cnt[NE], cur[NE];
        if (tid < NE) cnt[tid] = 0;
        __syncthreads();
        for (int t = tid; t < NTOK; t += 256) atomicAdd(&cnt[assign[t] & 7], 1);
        __syncthreads();
        if (tid == 0) {
            int o = 0;
            for (int e = 0; e < NE; e++) {
                meta[e] = cnt[e]; meta[16 + e] = o; cur[e] = o; o += cnt[e];
            }
        }
        __syncthreads();
        int* perm = meta + 512;
        for (int t = tid; t < NTOK; t += 256) {
            int e = assign[t] & 7;
            int p = atomicAdd(&cur[e], 1);
            perm[p] = t;
        }
        return;
    }
    if (b <= 8192) {
        long i = (long)(b - 1) * 256 + tid;
        const float4* s = (const float4*)(x + i * 8);
        float4 v0 = s[0], v1 = s[1];
        bf16x8 o;
        o[0] = (bf16)v0.x; o[1] = (bf16)v0.y; o[2] = (bf16)v0.z; o[3] = (bf16)v0.w;
        o[4] = (bf16)v1.x; o[5] = (bf16)v1.y; o[6] = (bf16)v1.z; o[7] = (bf16)v1.w;
        *(bf16x8*)(xb + i * 8) = o;
        return;
    }
    __shared__ float tile[32][33];
    int idx = b - 8193;
    const float* in; bf16* outp; int R, C, c0, r0;
    if (idx < 32768) {               // W_e[z]: R=ND, C=NH
        int z = idx >> 12, q = idx & 4095;
        int bx = q & 127, by = q >> 7;
        in = W_e + (size_t)z * ND * NH; outp = wte + (size_t)z * NH * ND;
        R = ND; C = NH; c0 = bx * 32; r0 = by * 32;
    } else {                          // W_out: R=NH, C=ND
        int q = idx - 32768;
        int bx = q & 31, by = q >> 5;
        in = W_out; outp = wto;
        R = NH; C = ND; c0 = bx * 32; r0 = by * 32;
    }
    int tx = tid & 31, ty = tid >> 5;
#pragma unroll
    for (int i = 0; i < 4; i++) {
        int r = r0 + ty + i * 8;
        tile[ty + i * 8][tx] = in[(size_t)r * C + c0 + tx];
    }
    __syncthreads();
#pragma unroll
    for (int i = 0; i < 4; i++) {
        int c = c0 + ty + i * 8;
        outp[(size_t)c * R + r0 + tx] = (bf16)tile[tx][ty + i * 8];
    }
}

// =====================================================================
// R6/R11-validated 8-phase 256x256 GEMM core, BK=64, 8 waves (2Mx4N).
// A: 3-deep ring [0,96K) staged t+2; B: 2-deep [96K,160K) staged t+2;
// vmcnt(8) once per K-tile; lgkmcnt(8) hint at p0 (12 ds_reads — m201).
// Operand region = 128 rows x 64k bf16 (128B rows); slot s of row r
// holds granule s^(r&7) (conflict-free XOR swizzle).
// =====================================================================

#define BAR { __builtin_amdgcn_s_barrier(); asm volatile("" ::: "memory"); }
#define VMC8 asm volatile("s_waitcnt vmcnt(8)" ::: "memory")
#define VMC0 asm volatile("s_waitcnt vmcnt(0)" ::: "memory")
#define LGKM8 asm volatile("s_waitcnt lgkmcnt(8)" ::: "memory")

#define LDA(msub) { \
  const char* Ab = sm + abuf + wr * 16384; \
  _Pragma("unroll") for (int m = 0; m < 4; m++) { \
    int row = ((msub) * 4 + m) * 16 + lr; \
    af[m][0] = *(const bf16x8*)(Ab + row * 128 + xk0); \
    af[m][1] = *(const bf16x8*)(Ab + row * 128 + xk1); \
  } }

#define LDB(nsub) { \
  const char* Bb = sm + bbuf + (wc >> 1) * 16384; \
  _Pragma("unroll") for (int n = 0; n < 2; n++) { \
    int row = (wc & 1) * 64 + ((nsub) * 2 + n) * 16 + lr; \
    bfr[(nsub)*2+n][0] = *(const bf16x8*)(Bb + row * 128 + xk0); \
    bfr[(nsub)*2+n][1] = *(const bf16x8*)(Bb + row * 128 + xk1); \
  } }

#define MFMA_Q(msub, nsub) { \
  __builtin_amdgcn_s_setprio(1); \
  _Pragma("unroll") for (int m = 0; m < 4; m++) \
  _Pragma("unroll") for (int n = 0; n < 2; n++) \
  _Pragma("unroll") for (int k = 0; k < 2; k++) \
    acc[(msub)*4+m][(nsub)*2+n] = __builtin_amdgcn_mfma_f32_16x16x32_bf16( \
        af[m][k], bfr[(nsub)*2+n][k], acc[(msub)*4+m][(nsub)*2+n], 0, 0, 0); \
  __builtin_amdgcn_s_setprio(0); }

#define DO_TILE(i, S0, S1, S2, S3, VW) { \
  const int abuf = ((i) % 3) * 32768; \
  const int bbuf = 98304 + ((i) & 1) * 32768; \
  LDA(0); LDB(0); S0; LGKM8; BAR; MFMA_Q(0,0); BAR; \
  LDB(1);         S1; BAR; MFMA_Q(0,1); BAR; \
  LDA(1);         S2; BAR; MFMA_Q(1,0); BAR; \
                  S3; VW; BAR; MFMA_Q(1,1); BAR; \
}

#define STAGE_A(t, h) { \
    char* d = sm + ((t) % 3) * 32768 + (h) * 16384 + wid * 1024; \
    GLDS16(srcA(t, h, 0), d); \
    GLDS16(srcA(t, h, 1), d + 8192); }
#define STAGE_B(t, h) { \
    char* d = sm + 98304 + ((t) & 1) * 32768 + (h) * 16384 + wid * 1024; \
    GLDS16(srcB(t, h, 0), d); \
    GLDS16(srcB(t, h, 1), d + 8192); }

__launch_bounds__(512, 2)
__global__ void k_gemm1(const bf16* __restrict__ xb, const bf16* __restrict__ wte,
                        const float* __restrict__ b_e, bf16* __restrict__ hb,
                        const int* __restrict__ meta) {
    __shared__ __align__(16) char sm[163840];
    // expert == XCD (f&7); j fastest within XCD (FETCH-optimal, R6/R11)
    int f = blockIdx.x;
    int e = f & 7, q = f >> 3;
    int jj = q % 9, bx = q / 9;
    int cnt = meta[e];
    int rs  = meta[16 + e] + jj * 256;
    int rc  = cnt - jj * 256; if (rc > 256) rc = 256;
    if (rc <= 0) return;
    int n0 = bx * 256;
    const int* perm = meta + 512;

    int tid = threadIdx.x;
    int lane = tid & 63, wid = tid >> 6;
    int wr = wid >> 2, wc = wid & 3;
    int lr = lane & 15, kg = lane >> 4;
    int xk0 = (kg ^ (lr & 7)) * 16;
    int xk1 = ((4 + kg) ^ (lr & 7)) * 16;

    int sr = tid >> 3, sl = tid & 7;
    int g = sl ^ (sr & 7);
    const bf16* pa[2][2];
#pragma unroll
    for (int h = 0; h < 2; h++)
#pragma unroll
      for (int rr = 0; rr < 2; rr++) {
        int arow = h * 128 + rr * 64 + sr;
        int p = rs + (arow < rc - 1 ? arow : rc - 1);
        pa[h][rr] = xb + (size_t)perm[p] * ND + g * 8;   // perm-indirect A
      }
    const bf16* pb0 = wte + ((size_t)e * NH + n0 + sr) * ND + g * 8;

#define srcA(t, h, rr) (pa[h][rr] + (size_t)(t) * 64)
#define srcB(t, h, rr) (pb0 + ((h) * 128 + (rr) * 64) * (size_t)ND + (size_t)(t) * 64)

    f32x4 acc[8][4] = {};
    bf16x8 af[4][2], bfr[4][2];
    const int NT = ND / 64;   // 16

    STAGE_A(0, 0); STAGE_A(0, 1); STAGE_B(0, 0); STAGE_B(0, 1);
    STAGE_A(1, 0); STAGE_A(1, 1); STAGE_B(1, 0); STAGE_B(1, 1);
    VMC8;
    BAR;

#pragma unroll 2
    for (int i = 0; i < NT - 2; i++)
        DO_TILE(i, STAGE_A(i + 2, 0), STAGE_A(i + 2, 1),
                   STAGE_B(i + 2, 0), STAGE_B(i + 2, 1), VMC8);
    DO_TILE(NT - 2, , , , , VMC0);
    DO_TILE(NT - 1, , , , , );

    // epilogue: bias + relu, bf16, permuted (dense) row order
    float bias[4];
#pragma unroll
    for (int n = 0; n < 4; n++) bias[n] = b_e[e * NH + n0 + wc * 64 + n * 16 + lr];
#pragma unroll
    for (int m = 0; m < 8; m++) {
#pragma unroll
        for (int rr = 0; rr < 4; rr++) {
            int row = wr * 128 + m * 16 + kg * 4 + rr;
            if (row < rc) {
                bf16* hp = hb + (size_t)(rs + row) * NH + n0 + wc * 64;
#pragma unroll
                for (int n = 0; n < 4; n++)
                    hp[n * 16 + lr] = (bf16)fmaxf(acc[m][n][rr] + bias[n], 0.0f);
            }
        }
    }
#undef srcA
#undef srcB
}

__launch_bounds__(512, 2)
__global__ void k_gemm2(const bf16* __restrict__ hb, const bf16* __restrict__ wto,
                        const float* __restrict__ b_out, const int* __restrict__ meta,
                        float* __restrict__ out) {
    __shared__ __align__(16) char sm[163840];
    // XCD mapping 16m x 2n per XCD: B working set = 2 panels = 4MB -> L2-fit
    int lin = blockIdx.x;
    int xcd = lin & 7, slot = lin >> 3;
    int by = (xcd & 3) * 16 + (slot >> 1);
    int bx = (xcd >> 2) * 2 + (slot & 1);
    int m0 = by * 256, n0 = bx * 256;
    const int* perm = meta + 512;

    int tid = threadIdx.x;
    int lane = tid & 63, wid = tid >> 6;
    int wr = wid >> 2, wc = wid & 3;
    int lr = lane & 15, kg = lane >> 4;
    int xk0 = (kg ^ (lr & 7)) * 16;
    int xk1 = ((4 + kg) ^ (lr & 7)) * 16;

    int sr = tid >> 3, sl = tid & 7;
    int g = sl ^ (sr & 7);
    const bf16* pa0 = hb  + ((size_t)m0 + sr) * NH + g * 8;
    const bf16* pb0 = wto + ((size_t)n0 + sr) * NH + g * 8;

#define srcA(t, h, rr) (pa0 + ((h) * 128 + (rr) * 64) * (size_t)NH + (size_t)(t) * 64)
#define srcB(t, h, rr) (pb0 + ((h) * 128 + (rr) * 64) * (size_t)NH + (size_t)(t) * 64)

    f32x4 acc[8][4] = {};
    bf16x8 af[4][2], bfr[4][2];
    const int NT = NH / 64;   // 64

    STAGE_A(0, 0); STAGE_A(0, 1); STAGE_B(0, 0); STAGE_B(0, 1);
    STAGE_A(1, 0); STAGE_A(1, 1); STAGE_B(1, 0); STAGE_B(1, 1);
    VMC8;
    BAR;

#pragma unroll 6
    for (int i = 0; i < NT - 2; i++)
        DO_TILE(i, STAGE_A(i + 2, 0), STAGE_A(i + 2, 1),
                   STAGE_B(i + 2, 0), STAGE_B(i + 2, 1), VMC8);
    DO_TILE(NT - 2, , , , , VMC0);
    DO_TILE(NT - 1, , , , , );

    // epilogue: bias, scatter rows to token order via perm
    float bias[4];
#pragma unroll
    for (int n = 0; n < 4; n++) bias[n] = b_out[n0 + wc * 64 + n * 16 + lr];
#pragma unroll
    for (int m = 0; m < 8; m++) {
#pragma unroll
        for (int rr = 0; rr < 4; rr++) {
            int prow = m0 + wr * 128 + m * 16 + kg * 4 + rr;
            int tok = perm[prow];
            float* op = out + (size_t)tok * ND + n0 + wc * 64;
#pragma unroll
            for (int n = 0; n < 4; n++)
                op[n * 16 + lr] = acc[m][n][rr] + bias[n];
        }
    }
#undef srcA
#undef srcB
}

extern "C" void kernel_launch(void* const* d_in, const int* in_sizes, int n_in,
                              void* d_out, int out_size, void* d_ws, size_t ws_size,
                              hipStream_t stream) {
    const float* x     = (const float*)d_in[0];
    const float* W_e   = (const float*)d_in[1];
    const float* b_e   = (const float*)d_in[2];
    const float* W_out = (const float*)d_in[3];
    const float* b_out = (const float*)d_in[4];
    const int*   assign = (const int*)d_in[5];
    float* out = (float*)d_out;

    if (ws_size < WS_NEED) return;

    char* ws = (char*)d_ws;
    int*  meta = (int*)ws;
    bf16* xb  = (bf16*)(ws + OFF_XB);
    bf16* wte = (bf16*)(ws + OFF_WTE);
    bf16* wto = (bf16*)(ws + OFF_WTO);
    bf16* hb  = (bf16*)(ws + OFF_HB);

    // ONE prep launch: route (1 blk) + x cvt (8192) + both transposes (36864)
    k_prep<<<45057, 256, 0, stream>>>(assign, x, W_e, W_out, meta, xb, wte, wto);
    // grouped GEMM1: 8 experts (==XCD) x (9 j fastest x 16 bx)
    k_gemm1<<<1152, 512, 0, stream>>>(xb, wte, b_e, hb, meta);
    // dense GEMM2: B-L2-resident XCD mapping, scatter at the end
    k_gemm2<<<256, 512, 0, stream>>>(hb, wto, b_out, meta, out);
}

// Round 13
// 399.049 us; speedup vs baseline: 1.0469x; 1.0469x over previous
//
#include <hip/hip_runtime.h>
#include <hip/hip_bf16.h>
#include <stdint.h>

// Problem dims (fixed)
#define NB 8
#define NS 2048
#define ND 1024
#define NH 4096
#define NE 8
#define NTOK (NB*NS)   // 16384 tokens

typedef __bf16 bf16;
typedef bf16 bf16x8 __attribute__((ext_vector_type(8)));
typedef float f32x4 __attribute__((ext_vector_type(4)));

// ws layout: meta[512] ints + perm[16384] at meta+512, then:
static const size_t OFF_XB  = 128 * 1024;                          // bf16 xb [NTOK][ND]  (token order)
static const size_t OFF_WTE = OFF_XB  + (size_t)NTOK * ND * 2;     // bf16 wte[NE][NH][ND]
static const size_t OFF_WTO = OFF_WTE + (size_t)NE * NH * ND * 2;  // bf16 wto[ND][NH]
static const size_t OFF_HB  = OFF_WTO + (size_t)ND * NH * 2;       // bf16 hb [NTOK][NH] (permuted rows)
static const size_t WS_NEED = OFF_HB  + (size_t)NTOK * NH * 2;

#define GLDS16(src, dst) __builtin_amdgcn_global_load_lds( \
    (__attribute__((address_space(1))) void*)(void*)(src), \
    (__attribute__((address_space(3))) void*)(dst), 16, 0, 0)

// =====================================================================
// ONE prep kernel (R11-validated, at HBM BW): block 0 = routing;
// blocks [1,8192] = x cvt; blocks [8193,45056] = weight transposes.
// =====================================================================
__global__ void k_prep(const int* __restrict__ assign, const float* __restrict__ x,
                       const float* __restrict__ W_e, const float* __restrict__ W_out,
                       int* __restrict__ meta, bf16* __restrict__ xb,
                       bf16* __restrict__ wte, bf16* __restrict__ wto) {
    int b = blockIdx.x;
    int tid = threadIdx.x;
    if (b == 0) {
        __shared__ int cnt[NE], cur[NE];
        if (tid < NE) cnt[tid] = 0;
        __syncthreads();
        for (int t = tid; t < NTOK; t += 256) atomicAdd(&cnt[assign[t] & 7], 1);
        __syncthreads();
        if (tid == 0) {
            int o = 0;
            for (int e = 0; e < NE; e++) {
                meta[e] = cnt[e]; meta[16 + e] = o; cur[e] = o; o += cnt[e];
            }
        }
        __syncthreads();
        int* perm = meta + 512;
        for (int t = tid; t < NTOK; t += 256) {
            int e = assign[t] & 7;
            int p = atomicAdd(&cur[e], 1);
            perm[p] = t;
        }
        return;
    }
    if (b <= 8192) {
        long i = (long)(b - 1) * 256 + tid;
        const float4* s = (const float4*)(x + i * 8);
        float4 v0 = s[0], v1 = s[1];
        bf16x8 o;
        o[0] = (bf16)v0.x; o[1] = (bf16)v0.y; o[2] = (bf16)v0.z; o[3] = (bf16)v0.w;
        o[4] = (bf16)v1.x; o[5] = (bf16)v1.y; o[6] = (bf16)v1.z; o[7] = (bf16)v1.w;
        *(bf16x8*)(xb + i * 8) = o;
        return;
    }
    __shared__ float tile[32][33];
    int idx = b - 8193;
    const float* in; bf16* outp; int R, C, c0, r0;
    if (idx < 32768) {               // W_e[z]: R=ND, C=NH
        int z = idx >> 12, q = idx & 4095;
        int bx = q & 127, by = q >> 7;
        in = W_e + (size_t)z * ND * NH; outp = wte + (size_t)z * NH * ND;
        R = ND; C = NH; c0 = bx * 32; r0 = by * 32;
    } else {                          // W_out: R=NH, C=ND
        int q = idx - 32768;
        int bx = q & 31, by = q >> 5;
        in = W_out; outp = wto;
        R = NH; C = ND; c0 = bx * 32; r0 = by * 32;
    }
    int tx = tid & 31, ty = tid >> 5;
#pragma unroll
    for (int i = 0; i < 4; i++) {
        int r = r0 + ty + i * 8;
        tile[ty + i * 8][tx] = in[(size_t)r * C + c0 + tx];
    }
    __syncthreads();
#pragma unroll
    for (int i = 0; i < 4; i++) {
        int c = c0 + ty + i * 8;
        outp[(size_t)c * R + r0 + tx] = (bf16)tile[tx][ty + i * 8];
    }
}

// =====================================================================
// 2-PHASE 256x256 GEMM core, BK=64, 8 waves (2Mx4N), per-wave 128x64.
// Phase A: ds_read bfr(all 4 n-frags) + af(m-half 0) | stage A(t+2) |
//          BAR | 32 MFMA (m0 x all n) | BAR
// Phase B: ds_read af(m-half 1) (bfr reused) | stage B(t+2) | vmcnt(8) |
//          BAR | 32 MFMA (m1 x all n) | BAR
// 4 barriers/K-tile (was 8); bfr read once (was twice); same VGPR set.
// A: 3-deep ring [0,96K) staged t+2; B: 2-deep [96K,160K) staged t+2
// (B(t+2) writes dbuf t&1 AFTER phase A's closing barrier drained all
// B-reads of tile t). vmcnt(8) at phase B: only tile-(t+2)'s 8 loads
// outstanding -> tile t+1 fully landed before its phase A reads.
// Operand region = 128 rows x 64k bf16 (128B rows); slot s of row r
// holds granule s^(r&7) (conflict-free XOR swizzle, verified).
// =====================================================================

#define BAR { __builtin_amdgcn_s_barrier(); asm volatile("" ::: "memory"); }
#define VMC8 asm volatile("s_waitcnt vmcnt(8)" ::: "memory")
#define VMC0 asm volatile("s_waitcnt vmcnt(0)" ::: "memory")

#define LDA_H(ms) { \
  const char* Ab = sm + abuf + wr * 16384; \
  _Pragma("unroll") for (int m = 0; m < 4; m++) { \
    int row = ((ms) * 4 + m) * 16 + lr; \
    af[m][0] = *(const bf16x8*)(Ab + row * 128 + xk0); \
    af[m][1] = *(const bf16x8*)(Ab + row * 128 + xk1); \
  } }

#define LDB_ALL { \
  const char* Bb = sm + bbuf + (wc >> 1) * 16384; \
  _Pragma("unroll") for (int n = 0; n < 4; n++) { \
    int row = (wc & 1) * 64 + n * 16 + lr; \
    bfr[n][0] = *(const bf16x8*)(Bb + row * 128 + xk0); \
    bfr[n][1] = *(const bf16x8*)(Bb + row * 128 + xk1); \
  } }

#define MFMA_H(ms) { \
  __builtin_amdgcn_s_setprio(1); \
  _Pragma("unroll") for (int m = 0; m < 4; m++) \
  _Pragma("unroll") for (int n = 0; n < 4; n++) \
  _Pragma("unroll") for (int k = 0; k < 2; k++) \
    acc[(ms)*4+m][n] = __builtin_amdgcn_mfma_f32_16x16x32_bf16( \
        af[m][k], bfr[n][k], acc[(ms)*4+m][n], 0, 0, 0); \
  __builtin_amdgcn_s_setprio(0); }

#define DO_TILE(i, SA, SB, VW) { \
  const int abuf = ((i) % 3) * 32768; \
  const int bbuf = 98304 + ((i) & 1) * 32768; \
  LDB_ALL; LDA_H(0); SA; BAR; MFMA_H(0); BAR; \
  LDA_H(1); SB; VW; BAR; MFMA_H(1); BAR; \
}

#define STAGE_A(t, h) { \
    char* d = sm + ((t) % 3) * 32768 + (h) * 16384 + wid * 1024; \
    GLDS16(srcA(t, h, 0), d); \
    GLDS16(srcA(t, h, 1), d + 8192); }
#define STAGE_B(t, h) { \
    char* d = sm + 98304 + ((t) & 1) * 32768 + (h) * 16384 + wid * 1024; \
    GLDS16(srcB(t, h, 0), d); \
    GLDS16(srcB(t, h, 1), d + 8192); }

__launch_bounds__(512, 2)
__global__ void k_gemm1(const bf16* __restrict__ xb, const bf16* __restrict__ wte,
                        const float* __restrict__ b_e, bf16* __restrict__ hb,
                        const int* __restrict__ meta) {
    __shared__ __align__(16) char sm[163840];
    // expert == XCD (f&7); j fastest within XCD (FETCH-optimal, R6/R11)
    int f = blockIdx.x;
    int e = f & 7, q = f >> 3;
    int jj = q % 9, bx = q / 9;
    int cnt = meta[e];
    int rs  = meta[16 + e] + jj * 256;
    int rc  = cnt - jj * 256; if (rc > 256) rc = 256;
    if (rc <= 0) return;
    int n0 = bx * 256;
    const int* perm = meta + 512;

    int tid = threadIdx.x;
    int lane = tid & 63, wid = tid >> 6;
    int wr = wid >> 2, wc = wid & 3;
    int lr = lane & 15, kg = lane >> 4;
    int xk0 = (kg ^ (lr & 7)) * 16;
    int xk1 = ((4 + kg) ^ (lr & 7)) * 16;

    int sr = tid >> 3, sl = tid & 7;
    int g = sl ^ (sr & 7);
    const bf16* pa[2][2];
#pragma unroll
    for (int h = 0; h < 2; h++)
#pragma unroll
      for (int rr = 0; rr < 2; rr++) {
        int arow = h * 128 + rr * 64 + sr;
        int p = rs + (arow < rc - 1 ? arow : rc - 1);
        pa[h][rr] = xb + (size_t)perm[p] * ND + g * 8;   // perm-indirect A
      }
    const bf16* pb0 = wte + ((size_t)e * NH + n0 + sr) * ND + g * 8;

#define srcA(t, h, rr) (pa[h][rr] + (size_t)(t) * 64)
#define srcB(t, h, rr) (pb0 + ((h) * 128 + (rr) * 64) * (size_t)ND + (size_t)(t) * 64)

    f32x4 acc[8][4] = {};
    bf16x8 af[4][2], bfr[4][2];
    const int NT = ND / 64;   // 16

    STAGE_A(0, 0); STAGE_A(0, 1); STAGE_B(0, 0); STAGE_B(0, 1);
    STAGE_A(1, 0); STAGE_A(1, 1); STAGE_B(1, 0); STAGE_B(1, 1);
    VMC8;
    BAR;

#pragma unroll 2
    for (int i = 0; i < NT - 2; i++)
        DO_TILE(i, STAGE_A(i + 2, 0) STAGE_A(i + 2, 1),
                   STAGE_B(i + 2, 0) STAGE_B(i + 2, 1), VMC8);
    DO_TILE(NT - 2, , , VMC0);
    DO_TILE(NT - 1, , , );

    // epilogue: bias + relu, bf16, permuted (dense) row order
    float bias[4];
#pragma unroll
    for (int n = 0; n < 4; n++) bias[n] = b_e[e * NH + n0 + wc * 64 + n * 16 + lr];
#pragma unroll
    for (int m = 0; m < 8; m++) {
#pragma unroll
        for (int rr = 0; rr < 4; rr++) {
            int row = wr * 128 + m * 16 + kg * 4 + rr;
            if (row < rc) {
                bf16* hp = hb + (size_t)(rs + row) * NH + n0 + wc * 64;
#pragma unroll
                for (int n = 0; n < 4; n++)
                    hp[n * 16 + lr] = (bf16)fmaxf(acc[m][n][rr] + bias[n], 0.0f);
            }
        }
    }
#undef srcA
#undef srcB
}

__launch_bounds__(512, 2)
__global__ void k_gemm2(const bf16* __restrict__ hb, const bf16* __restrict__ wto,
                        const float* __restrict__ b_out, const int* __restrict__ meta,
                        float* __restrict__ out) {
    __shared__ __align__(16) char sm[163840];
    int lin = blockIdx.x;
    int swz = (lin & 7) * 32 + (lin >> 3);   // bijective XCD swizzle (R11 best)
    int bx = swz & 3, by = swz >> 2;
    int m0 = by * 256, n0 = bx * 256;
    const int* perm = meta + 512;

    int tid = threadIdx.x;
    int lane = tid & 63, wid = tid >> 6;
    int wr = wid >> 2, wc = wid & 3;
    int lr = lane & 15, kg = lane >> 4;
    int xk0 = (kg ^ (lr & 7)) * 16;
    int xk1 = ((4 + kg) ^ (lr & 7)) * 16;

    int sr = tid >> 3, sl = tid & 7;
    int g = sl ^ (sr & 7);
    const bf16* pa0 = hb  + ((size_t)m0 + sr) * NH + g * 8;
    const bf16* pb0 = wto + ((size_t)n0 + sr) * NH + g * 8;

#define srcA(t, h, rr) (pa0 + ((h) * 128 + (rr) * 64) * (size_t)NH + (size_t)(t) * 64)
#define srcB(t, h, rr) (pb0 + ((h) * 128 + (rr) * 64) * (size_t)NH + (size_t)(t) * 64)

    f32x4 acc[8][4] = {};
    bf16x8 af[4][2], bfr[4][2];
    const int NT = NH / 64;   // 64

    STAGE_A(0, 0); STAGE_A(0, 1); STAGE_B(0, 0); STAGE_B(0, 1);
    STAGE_A(1, 0); STAGE_A(1, 1); STAGE_B(1, 0); STAGE_B(1, 1);
    VMC8;
    BAR;

#pragma unroll 6
    for (int i = 0; i < NT - 2; i++)
        DO_TILE(i, STAGE_A(i + 2, 0) STAGE_A(i + 2, 1),
                   STAGE_B(i + 2, 0) STAGE_B(i + 2, 1), VMC8);
    DO_TILE(NT - 2, , , VMC0);
    DO_TILE(NT - 1, , , );

    // epilogue: bias, scatter rows to token order via perm
    float bias[4];
#pragma unroll
    for (int n = 0; n < 4; n++) bias[n] = b_out[n0 + wc * 64 + n * 16 + lr];
#pragma unroll
    for (int m = 0; m < 8; m++) {
#pragma unroll
        for (int rr = 0; rr < 4; rr++) {
            int prow = m0 + wr * 128 + m * 16 + kg * 4 + rr;
            int tok = perm[prow];
            float* op = out + (size_t)tok * ND + n0 + wc * 64;
#pragma unroll
            for (int n = 0; n < 4; n++)
                op[n * 16 + lr] = acc[m][n][rr] + bias[n];
        }
    }
#undef srcA
#undef srcB
}

extern "C" void kernel_launch(void* const* d_in, const int* in_sizes, int n_in,
                              void* d_out, int out_size, void* d_ws, size_t ws_size,
                              hipStream_t stream) {
    const float* x     = (const float*)d_in[0];
    const float* W_e   = (const float*)d_in[1];
    const float* b_e   = (const float*)d_in[2];
    const float* W_out = (const float*)d_in[3];
    const float* b_out = (const float*)d_in[4];
    const int*   assign = (const int*)d_in[5];
    float* out = (float*)d_out;

    if (ws_size < WS_NEED) return;

    char* ws = (char*)d_ws;
    int*  meta = (int*)ws;
    bf16* xb  = (bf16*)(ws + OFF_XB);
    bf16* wte = (bf16*)(ws + OFF_WTE);
    bf16* wto = (bf16*)(ws + OFF_WTO);
    bf16* hb  = (bf16*)(ws + OFF_HB);

    // ONE prep launch: route (1 blk) + x cvt (8192) + both transposes (36864)
    k_prep<<<45057, 256, 0, stream>>>(assign, x, W_e, W_out, meta, xb, wte, wto);
    // grouped GEMM1: 8 experts (==XCD) x (9 j fastest x 16 bx)
    k_gemm1<<<1152, 512, 0, stream>>>(xb, wte, b_e, hb, meta);
    // dense GEMM2 over permuted hb rows, scatter at the end
    k_gemm2<<<256, 512, 0, stream>>>(hb, wto, b_out, meta, out);
}

// Round 14
// 394.619 us; speedup vs baseline: 1.0587x; 1.0112x over previous
//
#include <hip/hip_runtime.h>
#include <hip/hip_bf16.h>
#include <stdint.h>

// Problem dims (fixed)
#define NB 8
#define NS 2048
#define ND 1024
#define NH 4096
#define NE 8
#define NTOK (NB*NS)   // 16384 tokens

typedef __bf16 bf16;
typedef bf16 bf16x8 __attribute__((ext_vector_type(8)));
typedef float f32x4 __attribute__((ext_vector_type(4)));

// ws layout: meta[512] ints + perm[16384] at meta+512, then:
static const size_t OFF_XB  = 128 * 1024;                          // bf16 xb [NTOK][ND]  (token order)
static const size_t OFF_WTE = OFF_XB  + (size_t)NTOK * ND * 2;     // bf16 wte[NE][NH][ND]
static const size_t OFF_WTO = OFF_WTE + (size_t)NE * NH * ND * 2;  // bf16 wto[ND][NH]
static const size_t OFF_HB  = OFF_WTO + (size_t)ND * NH * 2;       // bf16 hb [NTOK][NH] (permuted rows)
static const size_t WS_NEED = OFF_HB  + (size_t)NTOK * NH * 2;

#define GLDS16(src, dst) __builtin_amdgcn_global_load_lds( \
    (__attribute__((address_space(1))) void*)(void*)(src), \
    (__attribute__((address_space(3))) void*)(dst), 16, 0, 0)

// =====================================================================
// ONE prep kernel (R11-validated, at HBM BW): block 0 = routing;
// blocks [1,8192] = x cvt; blocks [8193,45056] = weight transposes.
// =====================================================================
__global__ void k_prep(const int* __restrict__ assign, const float* __restrict__ x,
                       const float* __restrict__ W_e, const float* __restrict__ W_out,
                       int* __restrict__ meta, bf16* __restrict__ xb,
                       bf16* __restrict__ wte, bf16* __restrict__ wto) {
    int b = blockIdx.x;
    int tid = threadIdx.x;
    if (b == 0) {
        __shared__ int cnt[NE], cur[NE];
        if (tid < NE) cnt[tid] = 0;
        __syncthreads();
        for (int t = tid; t < NTOK; t += 256) atomicAdd(&cnt[assign[t] & 7], 1);
        __syncthreads();
        if (tid == 0) {
            int o = 0;
            for (int e = 0; e < NE; e++) {
                meta[e] = cnt[e]; meta[16 + e] = o; cur[e] = o; o += cnt[e];
            }
        }
        __syncthreads();
        int* perm = meta + 512;
        for (int t = tid; t < NTOK; t += 256) {
            int e = assign[t] & 7;
            int p = atomicAdd(&cur[e], 1);
            perm[p] = t;
        }
        return;
    }
    if (b <= 8192) {
        long i = (long)(b - 1) * 256 + tid;
        const float4* s = (const float4*)(x + i * 8);
        float4 v0 = s[0], v1 = s[1];
        bf16x8 o;
        o[0] = (bf16)v0.x; o[1] = (bf16)v0.y; o[2] = (bf16)v0.z; o[3] = (bf16)v0.w;
        o[4] = (bf16)v1.x; o[5] = (bf16)v1.y; o[6] = (bf16)v1.z; o[7] = (bf16)v1.w;
        *(bf16x8*)(xb + i * 8) = o;
        return;
    }
    __shared__ float tile[32][33];
    int idx = b - 8193;
    const float* in; bf16* outp; int R, C, c0, r0;
    if (idx < 32768) {               // W_e[z]: R=ND, C=NH
        int z = idx >> 12, q = idx & 4095;
        int bx = q & 127, by = q >> 7;
        in = W_e + (size_t)z * ND * NH; outp = wte + (size_t)z * NH * ND;
        R = ND; C = NH; c0 = bx * 32; r0 = by * 32;
    } else {                          // W_out: R=NH, C=ND
        int q = idx - 32768;
        int bx = q & 31, by = q >> 5;
        in = W_out; outp = wto;
        R = NH; C = ND; c0 = bx * 32; r0 = by * 32;
    }
    int tx = tid & 31, ty = tid >> 5;
#pragma unroll
    for (int i = 0; i < 4; i++) {
        int r = r0 + ty + i * 8;
        tile[ty + i * 8][tx] = in[(size_t)r * C + c0 + tx];
    }
    __syncthreads();
#pragma unroll
    for (int i = 0; i < 4; i++) {
        int c = c0 + ty + i * 8;
        outp[(size_t)c * R + r0 + tx] = (bf16)tile[tx][ty + i * 8];
    }
}

// =====================================================================
// Shared pieces. Operand region = 128 rows x 64k bf16 (128B rows);
// slot s of row r holds granule s^(r&7) (conflict-free XOR swizzle).
// A: 3-deep ring [0,96K) staged t+2; B: 2-deep [96K,160K) staged t+2;
// vmcnt(8) once per K-tile (only tile t+2's 8 loads outstanding at the
// wait -> tile t+1 fully landed).
// =====================================================================

#define BAR { __builtin_amdgcn_s_barrier(); asm volatile("" ::: "memory"); }
#define VMC8 asm volatile("s_waitcnt vmcnt(8)" ::: "memory")
#define VMC0 asm volatile("s_waitcnt vmcnt(0)" ::: "memory")

#define LDA_SUB(msub) { \
  const char* Ab = sm + abuf + wr * 16384; \
  _Pragma("unroll") for (int m = 0; m < 4; m++) { \
    int row = ((msub) * 4 + m) * 16 + lr; \
    af[m][0] = *(const bf16x8*)(Ab + row * 128 + xk0); \
    af[m][1] = *(const bf16x8*)(Ab + row * 128 + xk1); \
  } }

#define LDB_SUB(nsub) { \
  const char* Bb = sm + bbuf + (wc >> 1) * 16384; \
  _Pragma("unroll") for (int n = 0; n < 2; n++) { \
    int row = (wc & 1) * 64 + ((nsub) * 2 + n) * 16 + lr; \
    bfr[(nsub)*2+n][0] = *(const bf16x8*)(Bb + row * 128 + xk0); \
    bfr[(nsub)*2+n][1] = *(const bf16x8*)(Bb + row * 128 + xk1); \
  } }

#define LDB_ALL { \
  const char* Bb = sm + bbuf + (wc >> 1) * 16384; \
  _Pragma("unroll") for (int n = 0; n < 4; n++) { \
    int row = (wc & 1) * 64 + n * 16 + lr; \
    bfr[n][0] = *(const bf16x8*)(Bb + row * 128 + xk0); \
    bfr[n][1] = *(const bf16x8*)(Bb + row * 128 + xk1); \
  } }

#define MFMA_Q(msub, nsub) { \
  __builtin_amdgcn_s_setprio(1); \
  _Pragma("unroll") for (int m = 0; m < 4; m++) \
  _Pragma("unroll") for (int n = 0; n < 2; n++) \
  _Pragma("unroll") for (int k = 0; k < 2; k++) \
    acc[(msub)*4+m][(nsub)*2+n] = __builtin_amdgcn_mfma_f32_16x16x32_bf16( \
        af[m][k], bfr[(nsub)*2+n][k], acc[(msub)*4+m][(nsub)*2+n], 0, 0, 0); \
  __builtin_amdgcn_s_setprio(0); }

#define MFMA_H(ms) { \
  __builtin_amdgcn_s_setprio(1); \
  _Pragma("unroll") for (int m = 0; m < 4; m++) \
  _Pragma("unroll") for (int n = 0; n < 4; n++) \
  _Pragma("unroll") for (int k = 0; k < 2; k++) \
    acc[(ms)*4+m][n] = __builtin_amdgcn_mfma_f32_16x16x32_bf16( \
        af[m][k], bfr[n][k], acc[(ms)*4+m][n], 0, 0, 0); \
  __builtin_amdgcn_s_setprio(0); }

// 4-phase K-tile (R11 core — best for g1, K=1024)
#define DO_TILE4(i, S0, S1, S2, S3, VW) { \
  const int abuf = ((i) % 3) * 32768; \
  const int bbuf = 98304 + ((i) & 1) * 32768; \
  LDA_SUB(0); LDB_SUB(0); S0; BAR; MFMA_Q(0,0); BAR; \
  LDB_SUB(1);             S1; BAR; MFMA_Q(0,1); BAR; \
  LDA_SUB(1);             S2; BAR; MFMA_Q(1,0); BAR; \
                          S3; VW; BAR; MFMA_Q(1,1); BAR; \
}

// 2-phase K-tile (R13 core — best for g2, K=4096)
#define DO_TILE2(i, SA, SB, VW) { \
  const int abuf = ((i) % 3) * 32768; \
  const int bbuf = 98304 + ((i) & 1) * 32768; \
  LDB_ALL; LDA_SUB(0); SA; BAR; MFMA_H(0); BAR; \
  LDA_SUB(1); SB; VW; BAR; MFMA_H(1); BAR; \
}

#define STAGE_A(t, h) { \
    char* d = sm + ((t) % 3) * 32768 + (h) * 16384 + wid * 1024; \
    GLDS16(srcA(t, h, 0), d); \
    GLDS16(srcA(t, h, 1), d + 8192); }
#define STAGE_B(t, h) { \
    char* d = sm + 98304 + ((t) & 1) * 32768 + (h) * 16384 + wid * 1024; \
    GLDS16(srcB(t, h, 0), d); \
    GLDS16(srcB(t, h, 1), d + 8192); }

__launch_bounds__(512, 2)
__global__ void k_gemm1(const bf16* __restrict__ xb, const bf16* __restrict__ wte,
                        const float* __restrict__ b_e, bf16* __restrict__ hb,
                        const int* __restrict__ meta) {
    __shared__ __align__(16) char sm[163840];
    // expert == XCD (f&7); j fastest within XCD (FETCH-optimal, R6/R11)
    int f = blockIdx.x;
    int e = f & 7, q = f >> 3;
    int jj = q % 9, bx = q / 9;
    int cnt = meta[e];
    int rs  = meta[16 + e] + jj * 256;
    int rc  = cnt - jj * 256; if (rc > 256) rc = 256;
    if (rc <= 0) return;
    int n0 = bx * 256;
    const int* perm = meta + 512;

    int tid = threadIdx.x;
    int lane = tid & 63, wid = tid >> 6;
    int wr = wid >> 2, wc = wid & 3;
    int lr = lane & 15, kg = lane >> 4;
    int xk0 = (kg ^ (lr & 7)) * 16;
    int xk1 = ((4 + kg) ^ (lr & 7)) * 16;

    int sr = tid >> 3, sl = tid & 7;
    int g = sl ^ (sr & 7);
    const bf16* pa[2][2];
#pragma unroll
    for (int h = 0; h < 2; h++)
#pragma unroll
      for (int rr = 0; rr < 2; rr++) {
        int arow = h * 128 + rr * 64 + sr;
        int p = rs + (arow < rc - 1 ? arow : rc - 1);
        pa[h][rr] = xb + (size_t)perm[p] * ND + g * 8;   // perm-indirect A
      }
    const bf16* pb0 = wte + ((size_t)e * NH + n0 + sr) * ND + g * 8;

#define srcA(t, h, rr) (pa[h][rr] + (size_t)(t) * 64)
#define srcB(t, h, rr) (pb0 + ((h) * 128 + (rr) * 64) * (size_t)ND + (size_t)(t) * 64)

    f32x4 acc[8][4] = {};
    bf16x8 af[4][2], bfr[4][2];
    const int NT = ND / 64;   // 16

    STAGE_A(0, 0); STAGE_A(0, 1); STAGE_B(0, 0); STAGE_B(0, 1);
    STAGE_A(1, 0); STAGE_A(1, 1); STAGE_B(1, 0); STAGE_B(1, 1);
    VMC8;
    BAR;

#pragma unroll 2
    for (int i = 0; i < NT - 2; i++)
        DO_TILE4(i, STAGE_A(i + 2, 0), STAGE_A(i + 2, 1),
                    STAGE_B(i + 2, 0), STAGE_B(i + 2, 1), VMC8);
    DO_TILE4(NT - 2, , , , , VMC0);
    DO_TILE4(NT - 1, , , , , );

    // epilogue: bias + relu, bf16, permuted (dense) row order
    float bias[4];
#pragma unroll
    for (int n = 0; n < 4; n++) bias[n] = b_e[e * NH + n0 + wc * 64 + n * 16 + lr];
#pragma unroll
    for (int m = 0; m < 8; m++) {
#pragma unroll
        for (int rr = 0; rr < 4; rr++) {
            int row = wr * 128 + m * 16 + kg * 4 + rr;
            if (row < rc) {
                bf16* hp = hb + (size_t)(rs + row) * NH + n0 + wc * 64;
#pragma unroll
                for (int n = 0; n < 4; n++)
                    hp[n * 16 + lr] = (bf16)fmaxf(acc[m][n][rr] + bias[n], 0.0f);
            }
        }
    }
#undef srcA
#undef srcB
}

__launch_bounds__(512, 2)
__global__ void k_gemm2(const bf16* __restrict__ hb, const bf16* __restrict__ wto,
                        const float* __restrict__ b_out, const int* __restrict__ meta,
                        float* __restrict__ out) {
    __shared__ __align__(16) char sm[163840];
    int lin = blockIdx.x;
    int swz = (lin & 7) * 32 + (lin >> 3);   // bijective XCD swizzle, 256 blocks
    int bx = swz & 3, by = swz >> 2;
    int m0 = by * 256, n0 = bx * 256;
    const int* perm = meta + 512;

    int tid = threadIdx.x;
    int lane = tid & 63, wid = tid >> 6;
    int wr = wid >> 2, wc = wid & 3;
    int lr = lane & 15, kg = lane >> 4;
    int xk0 = (kg ^ (lr & 7)) * 16;
    int xk1 = ((4 + kg) ^ (lr & 7)) * 16;

    int sr = tid >> 3, sl = tid & 7;
    int g = sl ^ (sr & 7);
    const bf16* pa0 = hb  + ((size_t)m0 + sr) * NH + g * 8;
    const bf16* pb0 = wto + ((size_t)n0 + sr) * NH + g * 8;

#define srcA(t, h, rr) (pa0 + ((h) * 128 + (rr) * 64) * (size_t)NH + (size_t)(t) * 64)
#define srcB(t, h, rr) (pb0 + ((h) * 128 + (rr) * 64) * (size_t)NH + (size_t)(t) * 64)

    f32x4 acc[8][4] = {};
    bf16x8 af[4][2], bfr[4][2];
    const int NT = NH / 64;   // 64

    STAGE_A(0, 0); STAGE_A(0, 1); STAGE_B(0, 0); STAGE_B(0, 1);
    STAGE_A(1, 0); STAGE_A(1, 1); STAGE_B(1, 0); STAGE_B(1, 1);
    VMC8;
    BAR;

#pragma unroll 6
    for (int i = 0; i < NT - 2; i++)
        DO_TILE2(i, STAGE_A(i + 2, 0) STAGE_A(i + 2, 1),
                    STAGE_B(i + 2, 0) STAGE_B(i + 2, 1), VMC8);
    DO_TILE2(NT - 2, , , VMC0);
    DO_TILE2(NT - 1, , , );

    // epilogue: bias, scatter rows to token order via perm
    float bias[4];
#pragma unroll
    for (int n = 0; n < 4; n++) bias[n] = b_out[n0 + wc * 64 + n * 16 + lr];
#pragma unroll
    for (int m = 0; m < 8; m++) {
#pragma unroll
        for (int rr = 0; rr < 4; rr++) {
            int prow = m0 + wr * 128 + m * 16 + kg * 4 + rr;
            int tok = perm[prow];
            float* op = out + (size_t)tok * ND + n0 + wc * 64;
#pragma unroll
            for (int n = 0; n < 4; n++)
                op[n * 16 + lr] = acc[m][n][rr] + bias[n];
        }
    }
#undef srcA
#undef srcB
}

extern "C" void kernel_launch(void* const* d_in, const int* in_sizes, int n_in,
                              void* d_out, int out_size, void* d_ws, size_t ws_size,
                              hipStream_t stream) {
    const float* x     = (const float*)d_in[0];
    const float* W_e   = (const float*)d_in[1];
    const float* b_e   = (const float*)d_in[2];
    const float* W_out = (const float*)d_in[3];
    const float* b_out = (const float*)d_in[4];
    const int*   assign = (const int*)d_in[5];
    float* out = (float*)d_out;

    if (ws_size < WS_NEED) return;

    char* ws = (char*)d_ws;
    int*  meta = (int*)ws;
    bf16* xb  = (bf16*)(ws + OFF_XB);
    bf16* wte = (bf16*)(ws + OFF_WTE);
    bf16* wto = (bf16*)(ws + OFF_WTO);
    bf16* hb  = (bf16*)(ws + OFF_HB);

    // ONE prep launch: route (1 blk) + x cvt (8192) + both transposes (36864)
    k_prep<<<45057, 256, 0, stream>>>(assign, x, W_e, W_out, meta, xb, wte, wto);
    // grouped GEMM1 (4-phase core): 8 experts (==XCD) x (9 j fastest x 16 bx)
    k_gemm1<<<1152, 512, 0, stream>>>(xb, wte, b_e, hb, meta);
    // dense GEMM2 (2-phase core) over permuted hb rows, scatter at the end
    k_gemm2<<<256, 512, 0, stream>>>(hb, wto, b_out, meta, out);
}